// Round 5
// baseline (574.099 us; speedup 1.0000x reference)
//
#include <hip/hip_runtime.h>
#include <hip/hip_fp16.h>

// out[i] = sum_{j: seg[j]==i} cv[idx[j]], seg sorted ascending.
//
// R4: cv fp32 -> fp16 in d_ws (4 MB = one XCD L2) made gathers L2-resident
//     (FETCH 1.10 GB -> 185 MB) but dur only 307 -> 204 us: gather path bound.
// R5: gathers are ~99% L1-miss (random 2 B into 4 MB vs 32 KiB L1); normal
//     loads allocate a 64 B line per miss (~2 GB of L1 fill). Non-temporal
//     gathers (no L1 allocate) should delete that fill traffic. _Float16 is
//     used because __builtin_nontemporal_load rejects the __half struct.
//
// Streaming layout unchanged: wave loads 256 contiguous edges as one
// coalesced 1 KiB transaction (lane l owns edges base+4l..+3, 16 B vectors,
// non-temporal). Per-lane run-length + sorted-key segmented wave reduce;
// head lanes atomicAdd.

typedef int   vint4   __attribute__((ext_vector_type(4)));
typedef float vfloat4 __attribute__((ext_vector_type(4)));

#define BLOCK 256
#define G     4                         // 16B groups per thread
#define EDGES_PER_BLOCK (BLOCK * G * 4) // 4096

// ---- pre-pass: cv fp32 -> fp16 into workspace -------------------------------
__global__ __launch_bounds__(256) void cvt_f32_f16(
    const float* __restrict__ cv, _Float16* __restrict__ cvh, int M)
{
    int i4 = (blockIdx.x * blockDim.x + threadIdx.x) * 4;   // M % 4 == 0
    if (i4 >= M) return;
    vfloat4 v = *(const vfloat4*)(cv + i4);
    union { _Float16 h[4]; ushort4 u; } p;
    p.h[0] = (_Float16)v.x; p.h[1] = (_Float16)v.y;
    p.h[2] = (_Float16)v.z; p.h[3] = (_Float16)v.w;
    *(ushort4*)((unsigned short*)cvh + i4) = p.u;
}

// ---- main: gather + segmented sum ------------------------------------------
__global__ __launch_bounds__(BLOCK) void seg_gather_sum(
    const _Float16* __restrict__ cv,   // fp16 copy, L2-resident
    const int*      __restrict__ idx,
    const int*      __restrict__ seg,
    float*          __restrict__ out,
    int E)
{
    const int lane = threadIdx.x & 63;
    const int wave = threadIdx.x >> 6;
    const int wavesPerBlock = BLOCK / 64;
    const int waveBase = (blockIdx.x * wavesPerBlock + wave) * (G * 256);

    vint4 iv[G], sv[G];
    bool valid[G];
    #pragma unroll
    for (int g = 0; g < G; ++g) {
        int e4 = waveBase + g * 256 + lane * 4;   // E % 4 == 0
        valid[g] = (e4 < E);
        if (valid[g]) {
            iv[g] = __builtin_nontemporal_load((const vint4*)(idx + e4));
            sv[g] = __builtin_nontemporal_load((const vint4*)(seg + e4));
        } else {
            iv[g] = (vint4){0, 0, 0, 0};
            sv[g] = (vint4){-1, -1, -1, -1};
        }
    }

    // gathers: independent, non-temporal (no L1 line allocate on miss)
    float v[G][4];
    #pragma unroll
    for (int g = 0; g < G; ++g) {
        if (valid[g]) {
            v[g][0] = (float)__builtin_nontemporal_load(cv + iv[g].x);
            v[g][1] = (float)__builtin_nontemporal_load(cv + iv[g].y);
            v[g][2] = (float)__builtin_nontemporal_load(cv + iv[g].z);
            v[g][3] = (float)__builtin_nontemporal_load(cv + iv[g].w);
        } else {
            v[g][0] = v[g][1] = v[g][2] = v[g][3] = 0.f;
        }
    }

    #pragma unroll
    for (int g = 0; g < G; ++g) {
        const int s0 = sv[g].x, s1 = sv[g].y, s2 = sv[g].z, s3 = sv[g].w;
        int   key;
        float val;
        if (s0 == s3) {                       // pure lane (sorted => all equal)
            key = s0;
            val = (v[g][0] + v[g][1]) + (v[g][2] + v[g][3]);
        } else {                              // rare: close interior runs now
            int cur = s0; float run = v[g][0];
            if (s1 != cur) { atomicAdd(&out[cur], run); cur = s1; run = 0.f; }
            run += v[g][1];
            if (s2 != cur) { atomicAdd(&out[cur], run); cur = s2; run = 0.f; }
            run += v[g][2];
            if (s3 != cur) { atomicAdd(&out[cur], run); cur = s3; run = 0.f; }
            run += v[g][3];
            key = s3; val = run;              // last run stays open to the right
        }

        // sorted-key segmented wave reduce: first lane of each equal-key run
        // ends holding that run's total.
        #pragma unroll
        for (int d = 1; d < 64; d <<= 1) {
            int   k2 = __shfl_down(key, d);
            float v2 = __shfl_down(val, d);
            if (lane + d < 64 && k2 == key) val += v2;
        }
        const int  kprev = __shfl_up(key, 1);
        const bool head  = (lane == 0) || (kprev != key);
        if (head && key >= 0) atomicAdd(&out[key], val);
    }
}

extern "C" void kernel_launch(void* const* d_in, const int* in_sizes, int n_in,
                              void* d_out, int out_size, void* d_ws, size_t ws_size,
                              hipStream_t stream) {
    const float* cv  = (const float*)d_in[0];
    const int*   idx = (const int*)d_in[1];
    const int*   seg = (const int*)d_in[2];
    const int    M   = in_sizes[0];
    const int    E   = in_sizes[1];
    float* out = (float*)d_out;

    // harness poisons d_out to 0xAA before every timed launch -> zero it
    (void)hipMemsetAsync(out, 0, (size_t)out_size * sizeof(float), stream);

    _Float16* cvh = (_Float16*)d_ws;           // ws_size >= 4 MB (checked R4)
    const int cblocks = (M / 4 + 255) / 256;
    cvt_f32_f16<<<cblocks, 256, 0, stream>>>(cv, cvh, M);

    const int blocks = (E + EDGES_PER_BLOCK - 1) / EDGES_PER_BLOCK;
    seg_gather_sum<<<blocks, BLOCK, 0, stream>>>(cvh, idx, seg, out, E);
}

// Round 6
// 411.101 us; speedup vs baseline: 1.3965x; 1.3965x over previous
//
#include <hip/hip_runtime.h>
#include <hip/hip_fp16.h>

// out[i] = sum_{j: seg[j]==i} cv[idx[j]], seg sorted ascending.
//
// R4: cv fp32->fp16 in d_ws (4 MB = one XCD L2): FETCH 1.10 GB -> 185 MB,
//     dur 307 -> 204 us. Remaining cost: gather path.
// R5: FAILED - __builtin_nontemporal_load on the gathers set the nt bit,
//     which de-prioritizes the line in L2 too -> FETCH 722 MB, dur 353 us.
// R6: gathers via agent-scope relaxed atomic loads -> global_load_ushort sc0:
//     bypass (non-coherent) L1, ALLOCATE in L2. Tests the "2 GB of useless
//     L2->L1 64B line fills" hypothesis without losing L2 residency.
//
// Streaming layout unchanged: wave loads 256 contiguous edges as one
// coalesced 1 KiB transaction (lane l owns edges base+4l..+3, 16 B vectors,
// non-temporal - those really are stream-once). Per-lane run-length +
// sorted-key segmented wave reduce; head lanes atomicAdd.

typedef int   vint4   __attribute__((ext_vector_type(4)));
typedef float vfloat4 __attribute__((ext_vector_type(4)));

#define BLOCK 256
#define G     4                         // 16B groups per thread
#define EDGES_PER_BLOCK (BLOCK * G * 4) // 4096

// ---- pre-pass: cv fp32 -> fp16 into workspace -------------------------------
__global__ __launch_bounds__(256) void cvt_f32_f16(
    const float* __restrict__ cv, unsigned short* __restrict__ cvh, int M)
{
    int i4 = (blockIdx.x * blockDim.x + threadIdx.x) * 4;   // M % 4 == 0
    if (i4 >= M) return;
    vfloat4 v = *(const vfloat4*)(cv + i4);
    union { _Float16 h[4]; ushort4 u; } p;
    p.h[0] = (_Float16)v.x; p.h[1] = (_Float16)v.y;
    p.h[2] = (_Float16)v.z; p.h[3] = (_Float16)v.w;
    *(ushort4*)(cvh + i4) = p.u;
}

// agent-scope load: compiles to global_load_ushort ... sc0
// (L1 bypassed - it is not agent-coherent - line allocates in L2 only)
__device__ __forceinline__ float gather_cv(const unsigned short* cvh, int i) {
    unsigned short u = __hip_atomic_load(cvh + i, __ATOMIC_RELAXED,
                                         __HIP_MEMORY_SCOPE_AGENT);
    _Float16 h;
    __builtin_memcpy(&h, &u, sizeof(h));
    return (float)h;
}

// ---- main: gather + segmented sum ------------------------------------------
__global__ __launch_bounds__(BLOCK) void seg_gather_sum(
    const unsigned short* __restrict__ cv,   // fp16 copy, L2-resident
    const int*            __restrict__ idx,
    const int*            __restrict__ seg,
    float*                __restrict__ out,
    int E)
{
    const int lane = threadIdx.x & 63;
    const int wave = threadIdx.x >> 6;
    const int wavesPerBlock = BLOCK / 64;
    const int waveBase = (blockIdx.x * wavesPerBlock + wave) * (G * 256);

    vint4 iv[G], sv[G];
    bool valid[G];
    #pragma unroll
    for (int g = 0; g < G; ++g) {
        int e4 = waveBase + g * 256 + lane * 4;   // E % 4 == 0
        valid[g] = (e4 < E);
        if (valid[g]) {
            iv[g] = __builtin_nontemporal_load((const vint4*)(idx + e4));
            sv[g] = __builtin_nontemporal_load((const vint4*)(seg + e4));
        } else {
            iv[g] = (vint4){0, 0, 0, 0};
            sv[g] = (vint4){-1, -1, -1, -1};
        }
    }

    // gathers: independent; sc0 loads skip L1 (no 64B line fill per miss),
    // hit in L2 where the 4 MB fp16 cv is resident
    float v[G][4];
    #pragma unroll
    for (int g = 0; g < G; ++g) {
        if (valid[g]) {
            v[g][0] = gather_cv(cv, iv[g].x);
            v[g][1] = gather_cv(cv, iv[g].y);
            v[g][2] = gather_cv(cv, iv[g].z);
            v[g][3] = gather_cv(cv, iv[g].w);
        } else {
            v[g][0] = v[g][1] = v[g][2] = v[g][3] = 0.f;
        }
    }

    #pragma unroll
    for (int g = 0; g < G; ++g) {
        const int s0 = sv[g].x, s1 = sv[g].y, s2 = sv[g].z, s3 = sv[g].w;
        int   key;
        float val;
        if (s0 == s3) {                       // pure lane (sorted => all equal)
            key = s0;
            val = (v[g][0] + v[g][1]) + (v[g][2] + v[g][3]);
        } else {                              // rare: close interior runs now
            int cur = s0; float run = v[g][0];
            if (s1 != cur) { atomicAdd(&out[cur], run); cur = s1; run = 0.f; }
            run += v[g][1];
            if (s2 != cur) { atomicAdd(&out[cur], run); cur = s2; run = 0.f; }
            run += v[g][2];
            if (s3 != cur) { atomicAdd(&out[cur], run); cur = s3; run = 0.f; }
            run += v[g][3];
            key = s3; val = run;              // last run stays open to the right
        }

        // sorted-key segmented wave reduce: first lane of each equal-key run
        // ends holding that run's total.
        #pragma unroll
        for (int d = 1; d < 64; d <<= 1) {
            int   k2 = __shfl_down(key, d);
            float v2 = __shfl_down(val, d);
            if (lane + d < 64 && k2 == key) val += v2;
        }
        const int  kprev = __shfl_up(key, 1);
        const bool head  = (lane == 0) || (kprev != key);
        if (head && key >= 0) atomicAdd(&out[key], val);
    }
}

extern "C" void kernel_launch(void* const* d_in, const int* in_sizes, int n_in,
                              void* d_out, int out_size, void* d_ws, size_t ws_size,
                              hipStream_t stream) {
    const float* cv  = (const float*)d_in[0];
    const int*   idx = (const int*)d_in[1];
    const int*   seg = (const int*)d_in[2];
    const int    M   = in_sizes[0];
    const int    E   = in_sizes[1];
    float* out = (float*)d_out;

    // harness poisons d_out to 0xAA before every timed launch -> zero it
    (void)hipMemsetAsync(out, 0, (size_t)out_size * sizeof(float), stream);

    unsigned short* cvh = (unsigned short*)d_ws;   // ws_size >= 4 MB (R4-checked)
    const int cblocks = (M / 4 + 255) / 256;
    cvt_f32_f16<<<cblocks, 256, 0, stream>>>(cv, cvh, M);

    const int blocks = (E + EDGES_PER_BLOCK - 1) / EDGES_PER_BLOCK;
    seg_gather_sum<<<blocks, BLOCK, 0, stream>>>(cvh, idx, seg, out, E);
}

// Round 7
// 409.697 us; speedup vs baseline: 1.4013x; 1.0034x over previous
//
#include <hip/hip_runtime.h>
#include <hip/hip_fp16.h>

// out[i] = sum_{j: seg[j]==i} cv[idx[j]], seg sorted ascending.
//
// R4: cv fp32->fp16 in d_ws (4 MB = one XCD L2): FETCH 1.10 GB -> 185 MB,
//     dur 307 -> 204 us.
// R5: FAILED - nt on gathers evicts from L2/LLC too (FETCH 722 MB, 353 us).
// R6: sc0 agent-scope gathers (L1 bypass, L2 allocate): FETCH 183 MB, dur
//     EXACTLY R4's 204 us -> L1 exonerated; wall is L2/TCP service of 32M
//     random requests (8.2 req/cy/XCD vs ~14-16 ceiling).
// R7: test sub-word-rate hypothesis: gather the aligned DWORD cvw[i>>1]
//     (4 B naturally aligned) and extract the fp16 half in VALU. Same
//     request count + footprint; if 2 B requests were half-rate, dur should
//     drop toward ~120 us. If flat -> request-count roofline.
//
// Streaming layout: wave loads 256 contiguous edges as one coalesced 1 KiB
// transaction (lane l owns edges base+4l..+3, 16 B vectors, non-temporal).
// Per-lane run-length + sorted-key segmented wave reduce; head lane atomics.

typedef int   vint4   __attribute__((ext_vector_type(4)));
typedef float vfloat4 __attribute__((ext_vector_type(4)));

#define BLOCK 256
#define G     4                         // 16B groups per thread
#define EDGES_PER_BLOCK (BLOCK * G * 4) // 4096

// ---- pre-pass: cv fp32 -> fp16 into workspace -------------------------------
__global__ __launch_bounds__(256) void cvt_f32_f16(
    const float* __restrict__ cv, unsigned short* __restrict__ cvh, int M)
{
    int i4 = (blockIdx.x * blockDim.x + threadIdx.x) * 4;   // M % 4 == 0
    if (i4 >= M) return;
    vfloat4 v = *(const vfloat4*)(cv + i4);
    union { _Float16 h[4]; ushort4 u; } p;
    p.h[0] = (_Float16)v.x; p.h[1] = (_Float16)v.y;
    p.h[2] = (_Float16)v.z; p.h[3] = (_Float16)v.w;
    *(ushort4*)(cvh + i4) = p.u;
}

// dword gather: agent-scope (sc0 -> L1 bypass, L2 allocate), 4 B aligned.
// Extract the fp16 half indexed by bit0 of i in VALU.
__device__ __forceinline__ float gather_cv(const unsigned int* cvw, int i) {
    unsigned int w = __hip_atomic_load(cvw + (i >> 1), __ATOMIC_RELAXED,
                                       __HIP_MEMORY_SCOPE_AGENT);
    unsigned short u = (i & 1) ? (unsigned short)(w >> 16) : (unsigned short)w;
    _Float16 h;
    __builtin_memcpy(&h, &u, sizeof(h));
    return (float)h;
}

// ---- main: gather + segmented sum ------------------------------------------
__global__ __launch_bounds__(BLOCK) void seg_gather_sum(
    const unsigned int* __restrict__ cvw,   // fp16 copy viewed as dwords
    const int*          __restrict__ idx,
    const int*          __restrict__ seg,
    float*              __restrict__ out,
    int E)
{
    const int lane = threadIdx.x & 63;
    const int wave = threadIdx.x >> 6;
    const int wavesPerBlock = BLOCK / 64;
    const int waveBase = (blockIdx.x * wavesPerBlock + wave) * (G * 256);

    vint4 iv[G], sv[G];
    bool valid[G];
    #pragma unroll
    for (int g = 0; g < G; ++g) {
        int e4 = waveBase + g * 256 + lane * 4;   // E % 4 == 0
        valid[g] = (e4 < E);
        if (valid[g]) {
            iv[g] = __builtin_nontemporal_load((const vint4*)(idx + e4));
            sv[g] = __builtin_nontemporal_load((const vint4*)(seg + e4));
        } else {
            iv[g] = (vint4){0, 0, 0, 0};
            sv[g] = (vint4){-1, -1, -1, -1};
        }
    }

    // gathers: independent dword loads, L2-resident target
    float v[G][4];
    #pragma unroll
    for (int g = 0; g < G; ++g) {
        if (valid[g]) {
            v[g][0] = gather_cv(cvw, iv[g].x);
            v[g][1] = gather_cv(cvw, iv[g].y);
            v[g][2] = gather_cv(cvw, iv[g].z);
            v[g][3] = gather_cv(cvw, iv[g].w);
        } else {
            v[g][0] = v[g][1] = v[g][2] = v[g][3] = 0.f;
        }
    }

    #pragma unroll
    for (int g = 0; g < G; ++g) {
        const int s0 = sv[g].x, s1 = sv[g].y, s2 = sv[g].z, s3 = sv[g].w;
        int   key;
        float val;
        if (s0 == s3) {                       // pure lane (sorted => all equal)
            key = s0;
            val = (v[g][0] + v[g][1]) + (v[g][2] + v[g][3]);
        } else {                              // rare: close interior runs now
            int cur = s0; float run = v[g][0];
            if (s1 != cur) { atomicAdd(&out[cur], run); cur = s1; run = 0.f; }
            run += v[g][1];
            if (s2 != cur) { atomicAdd(&out[cur], run); cur = s2; run = 0.f; }
            run += v[g][2];
            if (s3 != cur) { atomicAdd(&out[cur], run); cur = s3; run = 0.f; }
            run += v[g][3];
            key = s3; val = run;              // last run stays open to the right
        }

        // sorted-key segmented wave reduce: first lane of each equal-key run
        // ends holding that run's total.
        #pragma unroll
        for (int d = 1; d < 64; d <<= 1) {
            int   k2 = __shfl_down(key, d);
            float v2 = __shfl_down(val, d);
            if (lane + d < 64 && k2 == key) val += v2;
        }
        const int  kprev = __shfl_up(key, 1);
        const bool head  = (lane == 0) || (kprev != key);
        if (head && key >= 0) atomicAdd(&out[key], val);
    }
}

extern "C" void kernel_launch(void* const* d_in, const int* in_sizes, int n_in,
                              void* d_out, int out_size, void* d_ws, size_t ws_size,
                              hipStream_t stream) {
    const float* cv  = (const float*)d_in[0];
    const int*   idx = (const int*)d_in[1];
    const int*   seg = (const int*)d_in[2];
    const int    M   = in_sizes[0];
    const int    E   = in_sizes[1];
    float* out = (float*)d_out;

    // harness poisons d_out to 0xAA before every timed launch -> zero it
    (void)hipMemsetAsync(out, 0, (size_t)out_size * sizeof(float), stream);

    unsigned short* cvh = (unsigned short*)d_ws;   // ws_size >= 4 MB (R4-checked)
    const int cblocks = (M / 4 + 255) / 256;
    cvt_f32_f16<<<cblocks, 256, 0, stream>>>(cv, cvh, M);

    const int blocks = (E + EDGES_PER_BLOCK - 1) / EDGES_PER_BLOCK;
    seg_gather_sum<<<blocks, BLOCK, 0, stream>>>((const unsigned int*)cvh,
                                                 idx, seg, out, E);
}